// Round 1
// baseline (2933.294 us; speedup 1.0000x reference)
//
#include <hip/hip_runtime.h>
#include <math.h>
#include <float.h>

#define DIM 768
#define HEADS 12
#define HD 64
#define HIDDEN 3072
#define SEQ 2048
#define BATCH 2
#define NTOK (BATCH * SEQ)   // 4096
#define QKVC (3 * DIM)       // 2304
#define LN_EPS 1e-5f
#define ATT_SCALE 0.125f     // 64^-0.5

// ---------------- LayerNorm: one block per row of 768 ----------------
__global__ __launch_bounds__(256) void ln_kernel(const float* __restrict__ x,
                                                 const float* __restrict__ g,
                                                 const float* __restrict__ bta,
                                                 float* __restrict__ out) {
    int row = blockIdx.x;
    int t = threadIdx.x;
    const float* xr = x + (size_t)row * DIM;
    float v0 = xr[t], v1 = xr[t + 256], v2 = xr[t + 512];
    __shared__ float red[256];
    red[t] = v0 + v1 + v2;
    __syncthreads();
    for (int off = 128; off > 0; off >>= 1) {
        if (t < off) red[t] += red[t + off];
        __syncthreads();
    }
    float mean = red[0] * (1.0f / DIM);
    __syncthreads();
    float d0 = v0 - mean, d1 = v1 - mean, d2 = v2 - mean;
    red[t] = d0 * d0 + d1 * d1 + d2 * d2;
    __syncthreads();
    for (int off = 128; off > 0; off >>= 1) {
        if (t < off) red[t] += red[t + off];
        __syncthreads();
    }
    float rstd = rsqrtf(red[0] * (1.0f / DIM) + LN_EPS);
    float* orow = out + (size_t)row * DIM;
    orow[t]       = d0 * rstd * g[t]       + bta[t];
    orow[t + 256] = d1 * rstd * g[t + 256] + bta[t + 256];
    orow[t + 512] = d2 * rstd * g[t + 512] + bta[t + 512];
}

__device__ __forceinline__ float gelu_f(float v) {
    return 0.5f * v * (1.0f + erff(v * 0.70710678118654752f));
}

// ---------------- GEMM-NT: C[m][n] = sum_k A[m][k] * B[n][k] ----------------
// 64x64 tile, 256 threads, 4x4 micro-tile, K-tile 16, LDS stored [k][m].
// EPI: 0 = plain, 1 = +bias +resid, 2 = +bias then GELU
template <int EPI>
__global__ __launch_bounds__(256) void gemm_nt(const float* __restrict__ A,
                                               const float* __restrict__ Bw,
                                               float* __restrict__ C,
                                               int M, int N, int K,
                                               const float* __restrict__ bias,
                                               const float* __restrict__ resid) {
    __shared__ float As[16][64];
    __shared__ float Bs[16][64];
    int t = threadIdx.x;
    int tx = t & 15, ty = t >> 4;
    int row0 = blockIdx.y * 64, col0 = blockIdx.x * 64;
    int lr = t >> 2;          // 0..63: tile row loaded by this thread
    int lc = (t & 3) * 4;     // 0/4/8/12: k-offset of the float4
    const float* Ap = A + (size_t)(row0 + lr) * K + lc;
    const float* Bp = Bw + (size_t)(col0 + lr) * K + lc;
    float acc[4][4] = {};
    for (int k0 = 0; k0 < K; k0 += 16) {
        float4 av = *(const float4*)(Ap + k0);
        float4 bv = *(const float4*)(Bp + k0);
        __syncthreads();
        As[lc + 0][lr] = av.x; As[lc + 1][lr] = av.y;
        As[lc + 2][lr] = av.z; As[lc + 3][lr] = av.w;
        Bs[lc + 0][lr] = bv.x; Bs[lc + 1][lr] = bv.y;
        Bs[lc + 2][lr] = bv.z; Bs[lc + 3][lr] = bv.w;
        __syncthreads();
#pragma unroll
        for (int kk = 0; kk < 16; ++kk) {
            float4 a4 = *(const float4*)&As[kk][ty * 4];
            float4 b4 = *(const float4*)&Bs[kk][tx * 4];
            float ar[4] = {a4.x, a4.y, a4.z, a4.w};
            float br[4] = {b4.x, b4.y, b4.z, b4.w};
#pragma unroll
            for (int i = 0; i < 4; ++i)
#pragma unroll
                for (int j = 0; j < 4; ++j) acc[i][j] += ar[i] * br[j];
        }
    }
    int c = col0 + tx * 4;
#pragma unroll
    for (int i = 0; i < 4; ++i) {
        int r = row0 + ty * 4 + i;
        float4 v = make_float4(acc[i][0], acc[i][1], acc[i][2], acc[i][3]);
        if (EPI == 1) {
            const float4 bb = *(const float4*)&bias[c];
            const float4 rr = *(const float4*)&resid[(size_t)r * N + c];
            v.x += bb.x + rr.x; v.y += bb.y + rr.y;
            v.z += bb.z + rr.z; v.w += bb.w + rr.w;
        } else if (EPI == 2) {
            const float4 bb = *(const float4*)&bias[c];
            v.x = gelu_f(v.x + bb.x); v.y = gelu_f(v.y + bb.y);
            v.z = gelu_f(v.z + bb.z); v.w = gelu_f(v.w + bb.w);
        }
        *(float4*)&C[(size_t)r * N + c] = v;
    }
}

// ---------------- Attention: 1 block = (b, h, 4 queries); wave w owns query w
__global__ __launch_bounds__(256) void attn_kernel(const float* __restrict__ qkv,
                                                   const int* __restrict__ mask,
                                                   float* __restrict__ y) {
    int qt = blockIdx.x;   // query tile 0..511
    int h  = blockIdx.y;   // head
    int b  = blockIdx.z;   // batch
    int t = threadIdx.x;
    int lane = t & 63, wave = t >> 6;
    __shared__ float sc[4][SEQ];     // scores then probabilities, 32 KB
    __shared__ float kt[64][65];     // K/V tile, padded stride
    __shared__ float qs[4][64];
    const float* base = qkv + (size_t)b * SEQ * QKVC;
    qs[wave][lane] = base[(size_t)(qt * 4 + wave) * QKVC + h * HD + lane];
    const float* kbase = base + DIM + h * HD;
    const float* vbase = base + 2 * DIM + h * HD;
    const int* mrow = mask + b * SEQ;

    float wmax = -FLT_MAX;
    for (int m0 = 0; m0 < SEQ; m0 += 64) {
        __syncthreads();
#pragma unroll
        for (int i = 0; i < 4; ++i) {
            int idx = i * 256 + t;
            int row = idx >> 4, c4 = (idx & 15) * 4;
            float4 kv = *(const float4*)(kbase + (size_t)(m0 + row) * QKVC + c4);
            kt[row][c4 + 0] = kv.x; kt[row][c4 + 1] = kv.y;
            kt[row][c4 + 2] = kv.z; kt[row][c4 + 3] = kv.w;
        }
        __syncthreads();
        float s = 0.f;
#pragma unroll
        for (int d = 0; d < 64; ++d) s += qs[wave][d] * kt[lane][d];
        s *= ATT_SCALE;
        if (mrow[m0 + lane] == 1) s = -FLT_MAX;
        sc[wave][m0 + lane] = s;
        wmax = fmaxf(wmax, s);
    }
#pragma unroll
    for (int off = 32; off > 0; off >>= 1)
        wmax = fmaxf(wmax, __shfl_xor(wmax, off));
    float lsum = 0.f;
    for (int m = lane; m < SEQ; m += 64) {
        float p = expf(sc[wave][m] - wmax);
        sc[wave][m] = p;
        lsum += p;
    }
#pragma unroll
    for (int off = 32; off > 0; off >>= 1)
        lsum += __shfl_xor(lsum, off);
    float rinv = 1.f / lsum;

    float acc = 0.f;
    for (int m0 = 0; m0 < SEQ; m0 += 64) {
        __syncthreads();
#pragma unroll
        for (int i = 0; i < 4; ++i) {
            int idx = i * 256 + t;
            int row = idx >> 4, c4 = (idx & 15) * 4;
            float4 vv = *(const float4*)(vbase + (size_t)(m0 + row) * QKVC + c4);
            kt[row][c4 + 0] = vv.x; kt[row][c4 + 1] = vv.y;
            kt[row][c4 + 2] = vv.z; kt[row][c4 + 3] = vv.w;
        }
        __syncthreads();
#pragma unroll
        for (int mm = 0; mm < 64; ++mm)
            acc += sc[wave][m0 + mm] * kt[mm][lane];
    }
    y[(size_t)(b * SEQ + qt * 4 + wave) * DIM + h * HD + lane] = acc * rinv;
}

extern "C" void kernel_launch(void* const* d_in, const int* in_sizes, int n_in,
                              void* d_out, int out_size, void* d_ws, size_t ws_size,
                              hipStream_t stream) {
    const float* x      = (const float*)d_in[0];
    const int*   mask   = (const int*)d_in[1];
    const float* ln1_g  = (const float*)d_in[2];
    const float* ln1_b  = (const float*)d_in[3];
    const float* qkv_w  = (const float*)d_in[4];
    const float* proj_w = (const float*)d_in[5];
    const float* proj_b = (const float*)d_in[6];
    const float* ln2_g  = (const float*)d_in[7];
    const float* ln2_b  = (const float*)d_in[8];
    const float* fc1_w  = (const float*)d_in[9];
    const float* fc1_b  = (const float*)d_in[10];
    const float* fc2_w  = (const float*)d_in[11];
    const float* fc2_b  = (const float*)d_in[12];
    float* out = (float*)d_out;

    // Workspace layout (floats):
    //   buf0 : [0,        3145728)  h -> attn y -> h2
    //   x1   : [3145728,  6291456)  post-attention residual stream
    //   shrd : [6291456, 18874368)  qkv buffer (9.4M, dead after attn)
    //                               then FC1 activations (12.6M) reuse it
    float* ws   = (float*)d_ws;
    float* buf0 = ws;
    float* x1   = ws + 3145728;
    float* qkvb = ws + 6291456;
    float* a1   = ws + 6291456;

    ln_kernel<<<NTOK, 256, 0, stream>>>(x, ln1_g, ln1_b, buf0);
    gemm_nt<0><<<dim3(QKVC / 64, NTOK / 64), 256, 0, stream>>>(
        buf0, qkv_w, qkvb, NTOK, QKVC, DIM, nullptr, nullptr);
    attn_kernel<<<dim3(SEQ / 4, HEADS, BATCH), 256, 0, stream>>>(qkvb, mask, buf0);
    gemm_nt<1><<<dim3(DIM / 64, NTOK / 64), 256, 0, stream>>>(
        buf0, proj_w, x1, NTOK, DIM, DIM, proj_b, x);
    ln_kernel<<<NTOK, 256, 0, stream>>>(x1, ln2_g, ln2_b, buf0);
    gemm_nt<2><<<dim3(HIDDEN / 64, NTOK / 64), 256, 0, stream>>>(
        buf0, fc1_w, a1, NTOK, HIDDEN, DIM, fc1_b, nullptr);
    gemm_nt<1><<<dim3(DIM / 64, NTOK / 64), 256, 0, stream>>>(
        a1, fc2_w, out, NTOK, DIM, HIDDEN, fc2_b, x1);
}

// Round 2
// 371.568 us; speedup vs baseline: 7.8944x; 7.8944x over previous
//
#include <hip/hip_runtime.h>
#include <math.h>
#include <float.h>

#define DIM 768
#define HEADS 12
#define HD 64
#define HIDDEN 3072
#define SEQ 2048
#define BATCH 2
#define NTOK (BATCH * SEQ)   // 4096
#define QKVC (3 * DIM)       // 2304
#define LN_EPS 1e-5f

typedef unsigned short u16;
typedef __attribute__((ext_vector_type(8))) __bf16 bf16x8;
typedef __attribute__((ext_vector_type(8))) unsigned short u16x8;
typedef __attribute__((ext_vector_type(4))) float f32x4;

__device__ __forceinline__ u16 f2bf(float f) {
    unsigned int u = __builtin_bit_cast(unsigned int, f);
    u += 0x7fffu + ((u >> 16) & 1u);
    return (u16)(u >> 16);
}

__device__ __forceinline__ f32x4 mfma16(u16x8 a, u16x8 b, f32x4 c) {
    return __builtin_amdgcn_mfma_f32_16x16x32_bf16(
        __builtin_bit_cast(bf16x8, a), __builtin_bit_cast(bf16x8, b), c, 0, 0, 0);
}

__device__ __forceinline__ void gl2lds16(const void* g, void* l) {
    __builtin_amdgcn_global_load_lds(
        (const __attribute__((address_space(1))) void*)g,
        (__attribute__((address_space(3))) void*)l, 16, 0, 0);
}

__device__ __forceinline__ float gelu_f(float v) {
    return 0.5f * v * (1.0f + erff(v * 0.70710678118654752f));
}

// ---------------- fp32 -> bf16 convert (weights) ----------------
__global__ __launch_bounds__(256) void cvt_bf16(const float* __restrict__ s,
                                                u16* __restrict__ d, int n) {
    int i = (blockIdx.x * 256 + threadIdx.x) * 4;
    if (i < n) {
        float4 v = *(const float4*)(s + i);
        ushort4 o;
        o.x = f2bf(v.x); o.y = f2bf(v.y); o.z = f2bf(v.z); o.w = f2bf(v.w);
        *(ushort4*)(d + i) = o;
    }
}

// ---------------- LayerNorm: fp32 in, bf16 out ----------------
__global__ __launch_bounds__(256) void ln_kernel(const float* __restrict__ x,
                                                 const float* __restrict__ g,
                                                 const float* __restrict__ bta,
                                                 u16* __restrict__ out) {
    int row = blockIdx.x;
    int t = threadIdx.x;
    const float* xr = x + (size_t)row * DIM;
    float v0 = xr[t], v1 = xr[t + 256], v2 = xr[t + 512];
    __shared__ float red[256];
    red[t] = v0 + v1 + v2;
    __syncthreads();
    for (int off = 128; off > 0; off >>= 1) {
        if (t < off) red[t] += red[t + off];
        __syncthreads();
    }
    float mean = red[0] * (1.0f / DIM);
    __syncthreads();
    float d0 = v0 - mean, d1 = v1 - mean, d2 = v2 - mean;
    red[t] = d0 * d0 + d1 * d1 + d2 * d2;
    __syncthreads();
    for (int off = 128; off > 0; off >>= 1) {
        if (t < off) red[t] += red[t + off];
        __syncthreads();
    }
    float rstd = rsqrtf(red[0] * (1.0f / DIM) + LN_EPS);
    u16* orow = out + (size_t)row * DIM;
    orow[t]       = f2bf(d0 * rstd * g[t]       + bta[t]);
    orow[t + 256] = f2bf(d1 * rstd * g[t + 256] + bta[t + 256]);
    orow[t + 512] = f2bf(d2 * rstd * g[t + 512] + bta[t + 512]);
}

// ---------------- MFMA GEMM: C = A (MxK) * Bw^T (Bw is NxK), bf16 in ----------------
// EPI 0: bf16 out plain; 1: fp32 out +bias+resid; 2: bf16 out gelu(v+bias)
template <int BM, int BN, int EPI>
__global__ __launch_bounds__(256) void mgemm(const u16* __restrict__ A,
                                             const u16* __restrict__ Bw,
                                             void* __restrict__ Cout,
                                             int N, int K,
                                             const float* __restrict__ bias,
                                             const float* __restrict__ resid) {
    constexpr int WM = BM / 2, WN = BN / 2, NI = WM / 16, NJ = WN / 16;
    constexpr int ACALLS = (BM * 64) / 4096;   // 1KB per wave-call
    constexpr int BCALLS = (BN * 64) / 4096;
    __shared__ u16 As[BM * 32];
    __shared__ u16 Bs[BN * 32];
    int t = threadIdx.x;
    int w = t >> 6, lane = t & 63;
    int quad = lane >> 4, m16 = lane & 15;
    int row0 = blockIdx.y * BM, col0 = blockIdx.x * BN;
    int lrow = lane >> 2;          // 0..15 rows per call
    int lkb = (lane & 3) * 16;     // byte within 64B row

    f32x4 acc[NI][NJ] = {};

    for (int k0 = 0; k0 < K; k0 += 32) {
        __syncthreads();
#pragma unroll
        for (int c = 0; c < ACALLS; ++c) {
            int off = (w * ACALLS + c) * 1024;                 // bytes into tile
            int r = (off >> 6) + lrow;
            const u16* g = A + (size_t)(row0 + r) * K + k0 + (lkb >> 1);
            gl2lds16(g, As + (off >> 1));                      // wave-uniform LDS base
        }
#pragma unroll
        for (int c = 0; c < BCALLS; ++c) {
            int off = (w * BCALLS + c) * 1024;
            int r = (off >> 6) + lrow;
            const u16* g = Bw + (size_t)(col0 + r) * K + k0 + (lkb >> 1);
            gl2lds16(g, Bs + (off >> 1));
        }
        __syncthreads();
        u16x8 af[NI], bfj[NJ];
#pragma unroll
        for (int i = 0; i < NI; ++i)
            af[i] = *(const u16x8*)(As + ((w >> 1) * WM + 16 * i + m16) * 32 + quad * 8);
#pragma unroll
        for (int j = 0; j < NJ; ++j)
            bfj[j] = *(const u16x8*)(Bs + ((w & 1) * WN + 16 * j + m16) * 32 + quad * 8);
#pragma unroll
        for (int i = 0; i < NI; ++i)
#pragma unroll
            for (int j = 0; j < NJ; ++j)
                acc[i][j] = mfma16(af[i], bfj[j], acc[i][j]);
    }

    int wr0 = row0 + (w >> 1) * WM, wc0 = col0 + (w & 1) * WN;
#pragma unroll
    for (int i = 0; i < NI; ++i)
#pragma unroll
        for (int j = 0; j < NJ; ++j) {
            int ccol = wc0 + 16 * j + m16;
#pragma unroll
            for (int r = 0; r < 4; ++r) {
                int crow = wr0 + 16 * i + quad * 4 + r;
                float v = acc[i][j][r];
                if (EPI == 0) {
                    ((u16*)Cout)[(size_t)crow * N + ccol] = f2bf(v);
                } else if (EPI == 1) {
                    v += bias[ccol] + resid[(size_t)crow * N + ccol];
                    ((float*)Cout)[(size_t)crow * N + ccol] = v;
                } else {
                    v = gelu_f(v + bias[ccol]);
                    ((u16*)Cout)[(size_t)crow * N + ccol] = f2bf(v);
                }
            }
        }
}

// ---------------- Flash attention, bf16 MFMA ----------------
// block = 64 queries of one (b,h); 4 waves x 16 q-rows; K-tile = 64 keys
__global__ __launch_bounds__(256) void attn_mfma(const u16* __restrict__ qkv,
                                                 const int* __restrict__ mask,
                                                 u16* __restrict__ y) {
    int qt = blockIdx.x, h = blockIdx.y, b = blockIdx.z;
    int t = threadIdx.x, w = t >> 6, lane = t & 63;
    int quad = lane >> 4, m16 = lane & 15;
    __shared__ u16 Ks[64 * 72];        // [key][dim], stride 72 (16B-aligned rows)
    __shared__ u16 Vt[64 * 72];        // [dim][key], transposed
    __shared__ u16 Pw[4][16 * 72];     // per-wave P round-trip
    const u16* base = qkv + (size_t)b * SEQ * QKVC;
    const u16* kq = base + DIM + h * HD;
    const u16* vq = base + 2 * DIM + h * HD;
    const int* mrow = mask + b * SEQ;

    // Q A-frags (scale applied to fp32 scores later)
    int qrow = qt * 64 + w * 16 + m16;
    const u16* qp = base + (size_t)qrow * QKVC + h * HD + quad * 8;
    u16x8 qf0 = *(const u16x8*)qp;
    u16x8 qf1 = *(const u16x8*)(qp + 32);

    float mrun[4], lrun[4];
    f32x4 O[4] = {};
#pragma unroll
    for (int r = 0; r < 4; ++r) { mrun[r] = -3e38f; lrun[r] = 0.f; }

    int skey = t >> 2, sd0 = (t & 3) * 16;        // K staging
    int vkey = (t & 31) * 2, vd0 = (t >> 5) * 8;  // V transpose staging

    for (int k0 = 0; k0 < SEQ; k0 += 64) {
        __syncthreads();
        {   // stage K tile [64][64] bf16, rows contiguous
            const u16* g = kq + (size_t)(k0 + skey) * QKVC + sd0;
            *(uint4*)(Ks + skey * 72 + sd0)     = *(const uint4*)g;
            *(uint4*)(Ks + skey * 72 + sd0 + 8) = *(const uint4*)(g + 8);
        }
        {   // stage V transposed: pack key pairs -> b32 writes (conflict-free)
            const u16* g0 = vq + (size_t)(k0 + vkey) * QKVC + vd0;
            u16x8 a = *(const u16x8*)g0;
            u16x8 c = *(const u16x8*)(g0 + QKVC);
#pragma unroll
            for (int j = 0; j < 8; ++j) {
                unsigned int pk = (unsigned int)a[j] | ((unsigned int)c[j] << 16);
                *(unsigned int*)(Vt + (vd0 + j) * 72 + vkey) = pk;
            }
        }
        float kbias[4];
#pragma unroll
        for (int nb = 0; nb < 4; ++nb)
            kbias[nb] = (mrow[k0 + m16 + 16 * nb] == 1) ? -1e30f : 0.f;
        __syncthreads();

        // S = Q*K^T (rows=q in D-layout, cols=key)
        float sv[4][4];   // [nb][r]
#pragma unroll
        for (int nb = 0; nb < 4; ++nb) {
            const u16* kr = Ks + (m16 + 16 * nb) * 72 + quad * 8;
            f32x4 sacc = {0.f, 0.f, 0.f, 0.f};
            sacc = mfma16(qf0, *(const u16x8*)kr, sacc);
            sacc = mfma16(qf1, *(const u16x8*)(kr + 32), sacc);
#pragma unroll
            for (int r = 0; r < 4; ++r) sv[nb][r] = sacc[r] * 0.125f + kbias[nb];
        }
        // online softmax, per q-row r (row stats shared across 16-lane quad)
        float tmax[4], al[4], psum[4];
#pragma unroll
        for (int r = 0; r < 4; ++r)
            tmax[r] = fmaxf(fmaxf(sv[0][r], sv[1][r]), fmaxf(sv[2][r], sv[3][r]));
#pragma unroll
        for (int off = 1; off < 16; off <<= 1)
#pragma unroll
            for (int r = 0; r < 4; ++r)
                tmax[r] = fmaxf(tmax[r], __shfl_xor(tmax[r], off));
#pragma unroll
        for (int r = 0; r < 4; ++r) {
            float mn = fmaxf(mrun[r], tmax[r]);
            al[r] = __expf(mrun[r] - mn);
            mrun[r] = mn;
            psum[r] = 0.f;
        }
        float pv[4][4];
#pragma unroll
        for (int nb = 0; nb < 4; ++nb)
#pragma unroll
            for (int r = 0; r < 4; ++r) {
                float p = __expf(sv[nb][r] - mrun[r]);
                pv[nb][r] = p;
                psum[r] += p;
            }
#pragma unroll
        for (int off = 1; off < 16; off <<= 1)
#pragma unroll
            for (int r = 0; r < 4; ++r)
                psum[r] += __shfl_xor(psum[r], off);
#pragma unroll
        for (int r = 0; r < 4; ++r) lrun[r] = lrun[r] * al[r] + psum[r];
#pragma unroll
        for (int nb = 0; nb < 4; ++nb)
#pragma unroll
            for (int r = 0; r < 4; ++r) O[nb][r] *= al[r];
        // P: D-layout -> LDS -> A-layout
#pragma unroll
        for (int nb = 0; nb < 4; ++nb)
#pragma unroll
            for (int r = 0; r < 4; ++r)
                Pw[w][(quad * 4 + r) * 72 + m16 + 16 * nb] = f2bf(pv[nb][r]);
        __syncthreads();
        const u16* pr = Pw[w] + m16 * 72 + quad * 8;
        u16x8 pf0 = *(const u16x8*)pr;
        u16x8 pf1 = *(const u16x8*)(pr + 32);
#pragma unroll
        for (int nb = 0; nb < 4; ++nb) {
            const u16* vr = Vt + (m16 + 16 * nb) * 72 + quad * 8;
            O[nb] = mfma16(pf0, *(const u16x8*)vr, O[nb]);
            O[nb] = mfma16(pf1, *(const u16x8*)(vr + 32), O[nb]);
        }
    }
    // epilogue: O row = quad*4+r, col(dim) = m16+16nb
#pragma unroll
    for (int r = 0; r < 4; ++r) {
        float inv = 1.0f / lrun[r];
        int tok = b * SEQ + qt * 64 + w * 16 + quad * 4 + r;
        u16* yr = y + (size_t)tok * DIM + h * HD + m16;
#pragma unroll
        for (int nb = 0; nb < 4; ++nb) yr[16 * nb] = f2bf(O[nb][r] * inv);
    }
}

extern "C" void kernel_launch(void* const* d_in, const int* in_sizes, int n_in,
                              void* d_out, int out_size, void* d_ws, size_t ws_size,
                              hipStream_t stream) {
    const float* x      = (const float*)d_in[0];
    const int*   mask   = (const int*)d_in[1];
    const float* ln1_g  = (const float*)d_in[2];
    const float* ln1_b  = (const float*)d_in[3];
    const float* qkv_w  = (const float*)d_in[4];
    const float* proj_w = (const float*)d_in[5];
    const float* proj_b = (const float*)d_in[6];
    const float* ln2_g  = (const float*)d_in[7];
    const float* ln2_b  = (const float*)d_in[8];
    const float* fc1_w  = (const float*)d_in[9];
    const float* fc1_b  = (const float*)d_in[10];
    const float* fc2_w  = (const float*)d_in[11];
    const float* fc2_b  = (const float*)d_in[12];
    float* out = (float*)d_out;

    // workspace layout (bytes)
    char* W = (char*)d_ws;
    u16*   wqkv  = (u16*)(W + 0);           // 2304x768   bf16
    u16*   wproj = (u16*)(W + 3538944);     // 768x768
    u16*   wfc1  = (u16*)(W + 4718592);     // 3072x768
    u16*   wfc2  = (u16*)(W + 9437184);     // 768x3072
    u16*   hbuf  = (u16*)(W + 14155776);    // 4096x768   bf16 (ln out, reused)
    float* x1    = (float*)(W + 20447232);  // 4096x768   fp32
    u16*   qkvb  = (u16*)(W + 33030144);    // 4096x2304  bf16
    u16*   ybuf  = (u16*)(W + 51904512);    // 4096x768   bf16
    u16*   a1    = (u16*)(W + 33030144);    // 4096x3072  bf16, aliases qkvb+ybuf (dead)

    cvt_bf16<<<1728, 256, 0, stream>>>(qkv_w, wqkv, 1769472);
    cvt_bf16<<<576,  256, 0, stream>>>(proj_w, wproj, 589824);
    cvt_bf16<<<2304, 256, 0, stream>>>(fc1_w, wfc1, 2359296);
    cvt_bf16<<<2304, 256, 0, stream>>>(fc2_w, wfc2, 2359296);

    ln_kernel<<<NTOK, 256, 0, stream>>>(x, ln1_g, ln1_b, hbuf);
    mgemm<128, 128, 0><<<dim3(QKVC / 128, NTOK / 128), 256, 0, stream>>>(
        hbuf, wqkv, qkvb, QKVC, DIM, nullptr, nullptr);
    attn_mfma<<<dim3(SEQ / 64, HEADS, BATCH), 256, 0, stream>>>(qkvb, mask, ybuf);
    mgemm<128, 64, 1><<<dim3(DIM / 64, NTOK / 128), 256, 0, stream>>>(
        ybuf, wproj, x1, DIM, DIM, proj_b, x);
    ln_kernel<<<NTOK, 256, 0, stream>>>(x1, ln2_g, ln2_b, hbuf);
    mgemm<128, 128, 2><<<dim3(HIDDEN / 128, NTOK / 128), 256, 0, stream>>>(
        hbuf, wfc1, a1, HIDDEN, DIM, fc1_b, nullptr);
    mgemm<128, 64, 1><<<dim3(DIM / 64, NTOK / 128), 256, 0, stream>>>(
        a1, wfc2, out, DIM, HIDDEN, fc2_b, x1);
}